// Round 4
// baseline (530118.262 us; speedup 1.0000x reference)
//
#include <hip/hip_runtime.h>

// ODE-RNN fused persistent kernel for MI355X (gfx950).
// B=1024, T=128, I=64, H=256, U=512, O=20, RK4_STEPS=8.
// 64 blocks x 512 threads; each block owns 16 batch rows, runs the entire
// sequential recurrence. ALL matmuls: bf16 MFMA 16x16x32 with 3-plane x
// 3-plane splitting, keeping product terms of level-sum <= 2 (6 MFMAs per
// logical matmul) -> ~2^-26 effective precision (better than f32 inputs).
// State h/z, RK4 combine, gates, biases: exact f32 in REGISTERS.
// Final projection: f64 accumulate.
// Weight planes staged in d_ws (bf16) when ws_size permits; otherwise split
// from f32 on the fly (template<bool STAGED> — same numerics, slower).

typedef __bf16 bf16_t;
typedef __bf16 bf16x8 __attribute__((ext_vector_type(8)));
typedef __bf16 bf16x4 __attribute__((ext_vector_type(4)));
typedef float  f32x4  __attribute__((ext_vector_type(4)));

#define NTHR 512
#define LD   2048  // LDS activation row stride (elements)
#define T_   128
#define I_   64

#define N_WIH (768*64)
#define N_WHH (768*256)
#define N_W1  (512*256)
#define N_W2  (512*512)
#define N_W3  (256*512)
// each weight: 3 contiguous planes H|M|L of N_* elements
#define OFF_WIH 0
#define OFF_WHH (OFF_WIH + 3*N_WIH)
#define OFF_W1  (OFF_WHH + 3*N_WHH)
#define OFF_W2  (OFF_W1 + 3*N_W1)
#define OFF_W3  (OFF_W2 + 3*N_W2)
#define WS_ELEMS (OFF_W3 + 3*N_W3)
#define WS_BYTES ((size_t)WS_ELEMS * 2)

// ---- prepass: f32 -> 3 bf16 planes (exact 24-bit split) ----
__global__ void cvt3(const float* __restrict__ s, bf16_t* __restrict__ d,
                     int n4, int nplane) {
  int i = blockIdx.x * 256 + threadIdx.x;
  if (i >= n4) return;
  float4 v = ((const float4*)s)[i];
  float vv[4] = {v.x, v.y, v.z, v.w};
  bf16x4 h, m, l;
#pragma unroll
  for (int j = 0; j < 4; j++) {
    bf16_t hi = (bf16_t)vv[j];
    float r1 = vv[j] - (float)hi;
    bf16_t mi = (bf16_t)r1;
    h[j] = hi; m[j] = mi;
    l[j] = (bf16_t)(r1 - (float)mi);
  }
  ((bf16x4*)d)[i] = h;
  ((bf16x4*)(d + nplane))[i] = m;
  ((bf16x4*)(d + 2 * nplane))[i] = l;
}

__device__ __forceinline__ float fast_tanh(float x) {
  float xc = fminf(fmaxf(x, -15.f), 15.f);
  float e = __expf(2.f * xc);
  return (e - 1.f) * __builtin_amdgcn_rcpf(e + 1.f);
}
__device__ __forceinline__ float fast_sigmoid(float x) {
  return __builtin_amdgcn_rcpf(1.f + __expf(-x));
}

// XOR swizzle (T2): spread rows across LDS 16B bank-slots
__device__ __forceinline__ int swz(int row, int e) {
  return row * LD + (e ^ ((row & 7) << 3));
}

// OUT[16, NT*16] += A[16,K] @ W[N,K]^T for tiles tile0..tile0+NT-1.
// A: 3 swizzled LDS planes at aoh/aom/aol. W: 3 bf16 planes (Wp, Wp+P, Wp+2P)
// if STAGED, else split from f32 Wf on the fly.
// 6 product terms (level-sum <= 2): hh, mh, hm, mm, lh, hl.
// C/D: col(n) = lane&15, row(m) = (lane>>4)*4 + reg.
template<int KSTEPS, int NT, bool STAGED>
__device__ __forceinline__ void mm33(const bf16_t* abuf, int aoh, int aom, int aol,
    const bf16_t* __restrict__ Wp, int P, const float* __restrict__ Wf,
    int K, int tile0, int lane, f32x4* acc)
{
  const int l15 = lane & 15, kg = lane >> 4;
  const int rowbase = l15 * LD;
  const int sw = (l15 & 7) << 3;
#pragma unroll
  for (int ks = 0; ks < KSTEPS; ks++) {
    const int kb = ks * 32 + kg * 8;
    bf16x8 ah = *(const bf16x8*)(abuf + rowbase + ((aoh + kb) ^ sw));
    bf16x8 am = *(const bf16x8*)(abuf + rowbase + ((aom + kb) ^ sw));
    bf16x8 al = *(const bf16x8*)(abuf + rowbase + ((aol + kb) ^ sw));
#pragma unroll
    for (int i = 0; i < NT; i++) {
      const size_t off = (size_t)((tile0 + i) * 16 + l15) * K + kb;
      bf16x8 bh, bm, bl;
      if (STAGED) {
        bh = *(const bf16x8*)(Wp + off);
        bm = *(const bf16x8*)(Wp + P + off);
        bl = *(const bf16x8*)(Wp + 2 * P + off);
      } else {
        const float* wp = Wf + off;
        float4 w0 = *(const float4*)wp, w1 = *(const float4*)(wp + 4);
        float wv[8] = {w0.x, w0.y, w0.z, w0.w, w1.x, w1.y, w1.z, w1.w};
#pragma unroll
        for (int j = 0; j < 8; j++) {
          bf16_t h = (bf16_t)wv[j];
          float r1 = wv[j] - (float)h;
          bf16_t m = (bf16_t)r1;
          bh[j] = h; bm[j] = m; bl[j] = (bf16_t)(r1 - (float)m);
        }
      }
      acc[i] = __builtin_amdgcn_mfma_f32_16x16x32_bf16(ah, bh, acc[i], 0, 0, 0);
      acc[i] = __builtin_amdgcn_mfma_f32_16x16x32_bf16(am, bh, acc[i], 0, 0, 0);
      acc[i] = __builtin_amdgcn_mfma_f32_16x16x32_bf16(ah, bm, acc[i], 0, 0, 0);
      acc[i] = __builtin_amdgcn_mfma_f32_16x16x32_bf16(am, bm, acc[i], 0, 0, 0);
      acc[i] = __builtin_amdgcn_mfma_f32_16x16x32_bf16(al, bh, acc[i], 0, 0, 0);
      acc[i] = __builtin_amdgcn_mfma_f32_16x16x32_bf16(ah, bl, acc[i], 0, 0, 0);
    }
  }
}

template<bool STAGED>
__global__ __launch_bounds__(NTHR) void odernn_main(
    const float* __restrict__ x, const float* __restrict__ times,
    const float* __restrict__ w_ih, const float* __restrict__ w_hh,
    const float* __restrict__ b_ih, const float* __restrict__ b_hh,
    const float* __restrict__ f_w1, const float* __restrict__ f_b1,
    const float* __restrict__ f_w2, const float* __restrict__ f_b2,
    const float* __restrict__ f_w3, const float* __restrict__ f_b3,
    const float* __restrict__ w_out, const float* __restrict__ b_out,
    const bf16_t* __restrict__ wsb, float* __restrict__ out)
{
  __shared__ bf16_t sh_A[16 * LD];    // 64 KB
  __shared__ bf16_t sh_B[16 * LD];    // 64 KB

  const int tid  = threadIdx.x;
  const int lane = tid & 63;
  const int wave = tid >> 6;          // 0..7
  const int l15  = lane & 15;
  const int row0 = (lane >> 4) * 4;   // C/D row base
  const int b0   = blockIdx.x * 16;

  const bf16_t* Wih = STAGED ? wsb + OFF_WIH : nullptr;
  const bf16_t* Whh = STAGED ? wsb + OFF_WHH : nullptr;
  const bf16_t* W1  = STAGED ? wsb + OFF_W1  : nullptr;
  const bf16_t* W2  = STAGED ? wsb + OFF_W2  : nullptr;
  const bf16_t* W3  = STAGED ? wsb + OFF_W3  : nullptr;

  // per-thread biases (each thread only ever needs its owned columns)
  float rb1[4], rb2[4], rb3[2];
  float vbir[2], vbiz[2], vbin[2], vbhr[2], vbhz[2], vbhn[2];
#pragma unroll
  for (int i = 0; i < 4; i++) {
    int c = (wave * 4 + i) * 16 + l15;
    rb1[i] = f_b1[c]; rb2[i] = f_b2[c];
  }
#pragma unroll
  for (int i = 0; i < 2; i++) {
    int c = (wave * 2 + i) * 16 + l15;
    rb3[i] = f_b3[c];
    vbir[i] = b_ih[c]; vbiz[i] = b_ih[256 + c]; vbin[i] = b_ih[512 + c];
    vbhr[i] = b_hh[c]; vbhz[i] = b_hh[256 + c]; vbhn[i] = b_hh[512 + c];
  }

  // f32 state in registers: this thread's 2 cols x 4 rows
  float hreg[2][4];
#pragma unroll
  for (int i = 0; i < 2; i++)
#pragma unroll
    for (int r = 0; r < 4; r++) hreg[i][r] = 0.f;

  // write v as 3 bf16 planes into buf at column offsets p0/p1/p2 + col
  auto put3 = [&](bf16_t* buf, int row, int p0, int p1, int p2, int col, float v) {
    bf16_t h = (bf16_t)v;
    float r1 = v - (float)h;
    bf16_t m = (bf16_t)r1;
    buf[swz(row, p0 + col)] = h;
    buf[swz(row, p1 + col)] = m;
    buf[swz(row, p2 + col)] = (bf16_t)(r1 - (float)m);
  };

  // One MLP eval: sh_A holds z 3-plane at 0/256/512. Output kc (own cols).
  auto mlp_eval = [&](float (&kc)[2][4]) {
    f32x4 acc[4];
#pragma unroll
    for (int i = 0; i < 4; i++) acc[i] = (f32x4){0.f, 0.f, 0.f, 0.f};
    mm33<8, 4, STAGED>(sh_A, 0, 256, 512, W1, N_W1, f_w1, 256, wave * 4, lane, acc);
#pragma unroll
    for (int i = 0; i < 4; i++) {       // h1 -> sh_B 3-plane (0/512/1024)
      int col = (wave * 4 + i) * 16 + l15;
#pragma unroll
      for (int r = 0; r < 4; r++)
        put3(sh_B, row0 + r, 0, 512, 1024, col, fast_tanh(acc[i][r] + rb1[i]));
    }
    __syncthreads();
#pragma unroll
    for (int i = 0; i < 4; i++) acc[i] = (f32x4){0.f, 0.f, 0.f, 0.f};
    mm33<16, 4, STAGED>(sh_B, 0, 512, 1024, W2, N_W2, f_w2, 512, wave * 4, lane, acc);
#pragma unroll
    for (int i = 0; i < 4; i++) {       // h2 -> sh_A 3-plane (0/512/1024)
      int col = (wave * 4 + i) * 16 + l15;
#pragma unroll
      for (int r = 0; r < 4; r++)
        put3(sh_A, row0 + r, 0, 512, 1024, col, fast_tanh(acc[i][r] + rb2[i]));
    }
    __syncthreads();
    f32x4 a3[2];
    a3[0] = (f32x4){0.f, 0.f, 0.f, 0.f};
    a3[1] = (f32x4){0.f, 0.f, 0.f, 0.f};
    mm33<16, 2, STAGED>(sh_A, 0, 512, 1024, W3, N_W3, f_w3, 512, wave * 2, lane, a3);
#pragma unroll
    for (int i = 0; i < 2; i++)
#pragma unroll
      for (int r = 0; r < 4; r++) kc[i][r] = a3[i][r] + rb3[i];
    __syncthreads();  // sh_A free for next stage
  };

  auto rk4_step = [&](float dt) {
    float kc[2][4] = {};
    float ka[2][4] = {};
#pragma unroll 1
    for (int st = 0; st < 4; st++) {
      float ci = (st == 0) ? 0.f : ((st == 3) ? dt : 0.5f * dt);
      float wt = (st == 1 || st == 2) ? 2.f : 1.f;
#pragma unroll
      for (int i = 0; i < 2; i++) {     // z_s -> sh_A 3-plane (0/256/512)
        int col = (wave * 2 + i) * 16 + l15;
#pragma unroll
        for (int r = 0; r < 4; r++)
          put3(sh_A, row0 + r, 0, 256, 512, col, hreg[i][r] + ci * kc[i][r]);
      }
      __syncthreads();
      mlp_eval(kc);
#pragma unroll
      for (int i = 0; i < 2; i++)
#pragma unroll
        for (int r = 0; r < 4; r++) ka[i][r] += wt * kc[i][r];
    }
    float c6 = dt * (1.f / 6.f);
#pragma unroll
    for (int i = 0; i < 2; i++)
#pragma unroll
      for (int r = 0; r < 4; r++) hreg[i][r] += c6 * ka[i][r];
  };

  auto gru_step = [&](int t) {
    // h -> sh_A 3-plane (0/256/512); x_t -> sh_B 3-plane (0/64/128)
#pragma unroll
    for (int i = 0; i < 2; i++) {
      int col = (wave * 2 + i) * 16 + l15;
#pragma unroll
      for (int r = 0; r < 4; r++)
        put3(sh_A, row0 + r, 0, 256, 512, col, hreg[i][r]);
    }
    if (tid < 256) {
      int m  = tid >> 4;
      int c4 = (tid & 15) << 2;
      float4 xv = *(const float4*)(x + (((size_t)(b0 + m)) * T_ + t) * I_ + c4);
      float vv[4] = {xv.x, xv.y, xv.z, xv.w};
      bf16x4 oh, om, ol;
#pragma unroll
      for (int j = 0; j < 4; j++) {
        bf16_t h = (bf16_t)vv[j];
        float r1 = vv[j] - (float)h;
        bf16_t m2 = (bf16_t)r1;
        oh[j] = h; om[j] = m2;
        ol[j] = (bf16_t)(r1 - (float)m2);
      }
      *(bf16x4*)(sh_B + swz(m, c4))       = oh;
      *(bf16x4*)(sh_B + swz(m, 64 + c4))  = om;
      *(bf16x4*)(sh_B + swz(m, 128 + c4)) = ol;
    }
    __syncthreads();
    f32x4 agh[3][2], agi[3][2];
#pragma unroll
    for (int s = 0; s < 3; s++) {
      agh[s][0] = (f32x4){0.f,0.f,0.f,0.f}; agh[s][1] = (f32x4){0.f,0.f,0.f,0.f};
      agi[s][0] = (f32x4){0.f,0.f,0.f,0.f}; agi[s][1] = (f32x4){0.f,0.f,0.f,0.f};
    }
#pragma unroll
    for (int s = 0; s < 3; s++) {
      int t0 = s * 16 + wave * 2;
      mm33<8, 2, STAGED>(sh_A, 0, 256, 512, Whh, N_WHH, w_hh, 256, t0, lane, agh[s]);
      mm33<2, 2, STAGED>(sh_B, 0, 64, 128, Wih, N_WIH, w_ih, 64, t0, lane, agi[s]);
    }
#pragma unroll
    for (int i = 0; i < 2; i++) {
#pragma unroll
      for (int r = 0; r < 4; r++) {
        float rg = fast_sigmoid(agi[0][i][r] + vbir[i] + agh[0][i][r] + vbhr[i]);
        float zg = fast_sigmoid(agi[1][i][r] + vbiz[i] + agh[1][i][r] + vbhz[i]);
        float nn = fast_tanh(agi[2][i][r] + vbin[i] + rg * (agh[2][i][r] + vbhn[i]));
        hreg[i][r] = (1.f - zg) * nn + zg * hreg[i][r];
      }
    }
    __syncthreads();  // all mm reads of sh_A/sh_B done before next overwrite
  };

  gru_step(0);
#pragma unroll 1
  for (int t = 1; t < T_; t++) {
    float dtf = (times[t] - times[t - 1]) * 0.125f;   // dt per RK4 step
#pragma unroll 1
    for (int s8 = 0; s8 < 8; s8++) rk4_step(dtf);
    gru_step(t);
  }

  // final: h (registers) -> f32 scratch in sh_A, then f64 projection
  float* shF = (float*)sh_A;   // 16*256 f32 = 16 KB
  __syncthreads();
#pragma unroll
  for (int i = 0; i < 2; i++) {
    int col = (wave * 2 + i) * 16 + l15;
#pragma unroll
    for (int r = 0; r < 4; r++) shF[(row0 + r) * 256 + col] = hreg[i][r];
  }
  __syncthreads();
  for (int idx = tid; idx < 16 * 20; idx += NTHR) {
    int m = idx / 20, o = idx - m * 20;
    double acc = (double)b_out[o];
    for (int k = 0; k < 256; k++)
      acc += (double)shF[m * 256 + k] * (double)w_out[o * 256 + k];
    out[(size_t)(b0 + m) * 20 + o] = (float)acc;
  }
}

extern "C" void kernel_launch(void* const* d_in, const int* in_sizes, int n_in,
                              void* d_out, int out_size, void* d_ws, size_t ws_size,
                              hipStream_t stream) {
  const float* x     = (const float*)d_in[0];
  const float* times = (const float*)d_in[1];
  const float* wih   = (const float*)d_in[2];
  const float* whh   = (const float*)d_in[3];
  const float* bih   = (const float*)d_in[4];
  const float* bhh   = (const float*)d_in[5];
  const float* fw1   = (const float*)d_in[6];
  const float* fb1   = (const float*)d_in[7];
  const float* fw2   = (const float*)d_in[8];
  const float* fb2   = (const float*)d_in[9];
  const float* fw3   = (const float*)d_in[10];
  const float* fb3   = (const float*)d_in[11];
  const float* wout  = (const float*)d_in[12];
  const float* bout  = (const float*)d_in[13];
  float* out = (float*)d_out;
  bf16_t* ws = (bf16_t*)d_ws;

  const bool staged = (ws_size >= WS_BYTES);
  if (staged) {
    int n4;
    n4 = N_WIH / 4; cvt3<<<(n4 + 255) / 256, 256, 0, stream>>>(wih, ws + OFF_WIH, n4, N_WIH);
    n4 = N_WHH / 4; cvt3<<<(n4 + 255) / 256, 256, 0, stream>>>(whh, ws + OFF_WHH, n4, N_WHH);
    n4 = N_W1  / 4; cvt3<<<(n4 + 255) / 256, 256, 0, stream>>>(fw1, ws + OFF_W1, n4, N_W1);
    n4 = N_W2  / 4; cvt3<<<(n4 + 255) / 256, 256, 0, stream>>>(fw2, ws + OFF_W2, n4, N_W2);
    n4 = N_W3  / 4; cvt3<<<(n4 + 255) / 256, 256, 0, stream>>>(fw3, ws + OFF_W3, n4, N_W3);
    odernn_main<true><<<64, NTHR, 0, stream>>>(x, times, wih, whh, bih, bhh,
                                               fw1, fb1, fw2, fb2, fw3, fb3,
                                               wout, bout, ws, out);
  } else {
    odernn_main<false><<<64, NTHR, 0, stream>>>(x, times, wih, whh, bih, bhh,
                                                fw1, fb1, fw2, fb2, fw3, fb3,
                                                wout, bout, ws, out);
  }
}